// Round 1
// baseline (1189.150 us; speedup 1.0000x reference)
//
#include <hip/hip_runtime.h>

#define B 16384
#define ENC_LEN 48
#define ENC_HID 128
#define T_DEC 12

__device__ __forceinline__ float fast_rcp(float x) { return __builtin_amdgcn_rcpf(x); }
__device__ __forceinline__ float fast_exp(float x) { return __expf(x); }
__device__ __forceinline__ float sigmoidf_(float x) { return fast_rcp(1.f + fast_exp(-x)); }
__device__ __forceinline__ float tanhf_(float x) {
    // 1 - 2/(e^{2x}+1); correct saturation for |x| large
    return 1.f - 2.f * fast_rcp(1.f + fast_exp(2.f * x));
}
__device__ __forceinline__ float nan_to_num_(float v) { return (v != v) ? 0.f : v; }
__device__ __forceinline__ float bperm(int byteidx, float v) {
    return __int_as_float(__builtin_amdgcn_ds_bpermute(byteidx, __float_as_int(v)));
}

// ---------------- precompute P (unchanged — HBM-bound at ~70 us) ----------------
// P[e*B + b] = float4( enc_row(e,b) . comb_W[i, 0:128] ), i = 0..3
__global__ __launch_bounds__(256) void precompute_P_kernel(
    const float* __restrict__ enc,    // (48, B, 128) f32
    const float* __restrict__ cW,     // (4, 132) f32
    float4* __restrict__ P)
{
    const int l = threadIdx.x & 7;
    const int rowLocal = threadIdx.x >> 3;

    float w[4][4][4];
    #pragma unroll
    for (int i = 0; i < 4; ++i)
        #pragma unroll
        for (int k = 0; k < 4; ++k) {
            float4 t = *(const float4*)(cW + i * 132 + k * 32 + l * 4);
            w[i][k][0] = t.x; w[i][k][1] = t.y; w[i][k][2] = t.z; w[i][k][3] = t.w;
        }

    const int totalRows = ENC_LEN * B;
    const int stride = gridDim.x * 32;
    for (int row = blockIdx.x * 32 + rowLocal; row < totalRows; row += stride) {
        const float* r = enc + (size_t)row * ENC_HID;
        float4 e[4];
        #pragma unroll
        for (int k = 0; k < 4; ++k)
            e[k] = *(const float4*)(r + k * 32 + l * 4);

        float a[4];
        #pragma unroll
        for (int i = 0; i < 4; ++i) {
            float s0 = e[0].x * w[i][0][0] + e[0].y * w[i][0][1] + e[0].z * w[i][0][2] + e[0].w * w[i][0][3];
            float s1 = e[1].x * w[i][1][0] + e[1].y * w[i][1][1] + e[1].z * w[i][1][2] + e[1].w * w[i][1][3];
            float s2 = e[2].x * w[i][2][0] + e[2].y * w[i][2][1] + e[2].z * w[i][2][2] + e[2].w * w[i][2][3];
            float s3 = e[3].x * w[i][3][0] + e[3].y * w[i][3][1] + e[3].z * w[i][3][2] + e[3].w * w[i][3][3];
            a[i] = (s0 + s1) + (s2 + s3);
        }
        #pragma unroll
        for (int m = 1; m < 8; m <<= 1) {
            #pragma unroll
            for (int i = 0; i < 4; ++i)
                a[i] += __shfl_xor(a[i], m, 8);
        }
        if (l == 0) P[row] = make_float4(a[0], a[1], a[2], a[3]);
    }
}

// ---------------- barrier-free decode ----------------
// 16 lanes per batch element (4 b per wave, 16 b per 256-thread block, grid 1024
// = 4 blocks/CU, 4 waves/SIMD). Lane q in [0,16) owns:
//   - attention rows e = 3q..3q+2
//   - GRU units g = q and q+16  (so the h-slice it produces is the h-slice it
//     owns next step: h lives entirely in registers, never in LDS)
// Cross-lane traffic per step: 32 ds_bpermute (ordered h[32] gather) +
// butterfly __shfl_xor reductions for {S, ctx0..3} and fc. ZERO __syncthreads
// in the main loop. Weights staged once into LDS, rows padded to 36 floats
// (16B-aligned; 16 unique row addresses per read spread across bank quads).
__global__ __launch_bounds__(256, 4) void decode_kernel(
    const float* __restrict__ y,        // (B,13,4)
    const float* __restrict__ hidden,   // (B,32)
    const float4* __restrict__ P,       // (48,B) f32x4
    const float* __restrict__ aW,       // (48,36)
    const float* __restrict__ ab,       // (48)
    const float* __restrict__ cW,       // (4,132)
    const float* __restrict__ cb,       // (4)
    const float* __restrict__ wih,      // (96,4)
    const float* __restrict__ whh,      // (96,32)
    const float* __restrict__ bih,      // (96)
    const float* __restrict__ bhh,      // (96)
    const float* __restrict__ fW,       // (32)
    const float* __restrict__ fb,       // (1)
    float* __restrict__ out)            // (12,B)
{
    __shared__ __align__(16) float aW_l[48 * 36];    // row e: [0:4]=x-w, [4:36]=h-w
    __shared__ __align__(16) float whh_l[96 * 36];   // row r: [0:32] used, pad 4
    __shared__ __align__(16) float wih_l[96 * 4];
    __shared__ float bih_l[96], bhh_l[96], ab_l[48], fW_l[32], cWt_l[16], cb_l[4];

    const int tid = threadIdx.x;

    // ---- one-time weight staging (only sync in the kernel) ----
    for (int i = tid; i < 48 * 36; i += 256) aW_l[i] = aW[i];
    for (int i = tid; i < 96 * 32; i += 256) whh_l[(i >> 5) * 36 + (i & 31)] = whh[i];
    for (int i = tid; i < 96 * 4; i += 256) wih_l[i] = wih[i];
    if (tid < 96) { bih_l[tid] = bih[tid]; bhh_l[tid] = bhh[tid]; }
    if (tid < 48) ab_l[tid] = ab[tid];
    if (tid < 32) fW_l[tid] = fW[tid];
    if (tid < 16) cWt_l[tid] = cW[(tid >> 2) * 132 + 128 + (tid & 3)];
    if (tid < 4)  cb_l[tid] = cb[tid];

    const int lane  = tid & 63;
    const int q     = lane & 15;                 // role within 16-lane group
    const int b     = blockIdx.x * 16 + (tid >> 4);
    const int pbase = (lane & 48) << 2;          // ds_bpermute group base (bytes)

    // preload t-invariant P fragments for this lane's 3 attention rows
    float4 pb0 = P[(size_t)(3 * q + 0) * B + b];
    float4 pb1 = P[(size_t)(3 * q + 1) * B + b];
    float4 pb2 = P[(size_t)(3 * q + 2) * B + b];

    // h slice owned by this lane (units q, q+16), in registers for all 12 steps
    float h0 = hidden[(size_t)b * 32 + q];
    float h1 = hidden[(size_t)b * 32 + q + 16];

    float xA0 = nan_to_num_(y[(size_t)b * 52 + 0]);
    float xA1 = nan_to_num_(y[(size_t)b * 52 + 1]);
    float xA2 = nan_to_num_(y[(size_t)b * 52 + 2]);
    float xA3 = nan_to_num_(y[(size_t)b * 52 + 3]);

    __syncthreads();

    const float fb0 = fb[0];

    #pragma unroll 1
    for (int t = 0; t < T_DEC; ++t) {
        // prefetch next y row early (hides HBM/L2 latency under this step)
        float4 yv = make_float4(0.f, 0.f, 0.f, 0.f);
        if (t < T_DEC - 1) yv = *(const float4*)(y + (size_t)b * 52 + (t + 1) * 4);

        // ---- ordered all-gather of h[32] within the 16-lane group ----
        float hf[32];
        #pragma unroll
        for (int j = 0; j < 16; ++j) hf[j] = bperm(pbase + (j << 2), h0);
        #pragma unroll
        for (int j = 0; j < 16; ++j) hf[16 + j] = bperm(pbase + (j << 2), h1);

        // ---- attention rows 3q..3q+2: logits -> exp -> softmax partials ----
        float Sp = 0.f, c0 = 0.f, c1 = 0.f, c2 = 0.f, c3 = 0.f;
        #pragma unroll
        for (int i = 0; i < 3; ++i) {
            const int e = 3 * q + i;
            const float4* wr = (const float4*)(aW_l + e * 36);
            float4 w0 = wr[0];
            float s = ab_l[e] + w0.x * xA0 + w0.y * xA1 + w0.z * xA2 + w0.w * xA3;
            #pragma unroll
            for (int c = 0; c < 8; ++c) {
                float4 wc = wr[1 + c];
                s += wc.x * hf[4 * c] + wc.y * hf[4 * c + 1]
                   + wc.z * hf[4 * c + 2] + wc.w * hf[4 * c + 3];
            }
            float g = fast_exp(s);
            Sp += g;
            float4 pbv = (i == 0) ? pb0 : ((i == 1) ? pb1 : pb2);
            c0 += g * pbv.x; c1 += g * pbv.y; c2 += g * pbv.z; c3 += g * pbv.w;
        }
        // butterfly-reduce {S, c0..c3} across the 16-lane group (all lanes get sums)
        #pragma unroll
        for (int m = 1; m < 16; m <<= 1) {
            Sp += __shfl_xor(Sp, m);
            c0 += __shfl_xor(c0, m);
            c1 += __shfl_xor(c1, m);
            c2 += __shfl_xor(c2, m);
            c3 += __shfl_xor(c3, m);
        }
        const float rs = fast_rcp(Sp);

        float x2[4];
        {
            float cc[4] = { c0, c1, c2, c3 };
            #pragma unroll
            for (int i = 0; i < 4; ++i)
                x2[i] = cc[i] * rs
                      + cWt_l[i * 4 + 0] * xA0 + cWt_l[i * 4 + 1] * xA1
                      + cWt_l[i * 4 + 2] * xA2 + cWt_l[i * 4 + 3] * xA3 + cb_l[i];
        }

        // ---- GRU units q and q+16 ----
        float hn0, hn1;
        #pragma unroll
        for (int u = 0; u < 2; ++u) {
            const int g = q + 16 * u;
            const float hu = (u == 0) ? h0 : h1;
            const float4* w4r = (const float4*)(whh_l + (size_t)g * 36);
            const float4* w4z = (const float4*)(whh_l + (size_t)(g + 32) * 36);
            const float4* w4n = (const float4*)(whh_l + (size_t)(g + 64) * 36);
            float hr = bhh_l[g], hz = bhh_l[g + 32], hn_ = bhh_l[g + 64];
            #pragma unroll
            for (int c = 0; c < 8; ++c) {
                float4 a = w4r[c], bz = w4z[c], cn = w4n[c];
                hr  += a.x  * hf[4 * c] + a.y  * hf[4 * c + 1] + a.z  * hf[4 * c + 2] + a.w  * hf[4 * c + 3];
                hz  += bz.x * hf[4 * c] + bz.y * hf[4 * c + 1] + bz.z * hf[4 * c + 2] + bz.w * hf[4 * c + 3];
                hn_ += cn.x * hf[4 * c] + cn.y * hf[4 * c + 1] + cn.z * hf[4 * c + 2] + cn.w * hf[4 * c + 3];
            }
            const float4 wiR = *(const float4*)(wih_l + (size_t)g * 4);
            const float4 wiZ = *(const float4*)(wih_l + (size_t)(g + 32) * 4);
            const float4 wiN = *(const float4*)(wih_l + (size_t)(g + 64) * 4);
            float ir  = bih_l[g]      + wiR.x * x2[0] + wiR.y * x2[1] + wiR.z * x2[2] + wiR.w * x2[3];
            float iz  = bih_l[g + 32] + wiZ.x * x2[0] + wiZ.y * x2[1] + wiZ.z * x2[2] + wiZ.w * x2[3];
            float in_ = bih_l[g + 64] + wiN.x * x2[0] + wiN.y * x2[1] + wiN.z * x2[2] + wiN.w * x2[3];
            float r = sigmoidf_(ir + hr);
            float z = sigmoidf_(iz + hz);
            float n = tanhf_(in_ + r * hn_);
            float hnv = (1.f - z) * n + z * hu;
            if (u == 0) hn0 = hnv; else hn1 = hnv;
        }

        // ---- fc output (butterfly reduce; every lane gets o for the x feedback) ----
        float op = fW_l[q] * hn0 + fW_l[q + 16] * hn1;
        #pragma unroll
        for (int m = 1; m < 16; m <<= 1) op += __shfl_xor(op, m);
        const float o = op + fb0;
        if (q == 0) out[(size_t)t * B + b] = o;

        h0 = hn0; h1 = hn1;
        if (t < T_DEC - 1) { xA0 = yv.y; xA1 = yv.z; xA2 = yv.w; xA3 = o; }
    }
}

extern "C" void kernel_launch(void* const* d_in, const int* in_sizes, int n_in,
                              void* d_out, int out_size, void* d_ws, size_t ws_size,
                              hipStream_t stream)
{
    const float* y   = (const float*)d_in[0];
    const float* enc = (const float*)d_in[1];
    const float* hid = (const float*)d_in[2];
    // d_in[3] = batch_ids (int32, unused by reference)
    const float* aW  = (const float*)d_in[4];
    const float* ab  = (const float*)d_in[5];
    const float* cW  = (const float*)d_in[6];
    const float* cb  = (const float*)d_in[7];
    const float* wih = (const float*)d_in[8];
    const float* whh = (const float*)d_in[9];
    const float* bih = (const float*)d_in[10];
    const float* bhh = (const float*)d_in[11];
    const float* fW  = (const float*)d_in[12];
    const float* fb  = (const float*)d_in[13];
    float* out = (float*)d_out;

    float4* P = (float4*)d_ws;   // 48*B float4 = 12.58 MB (ws proved sufficient)

    precompute_P_kernel<<<4096, 256, 0, stream>>>(enc, cW, P);
    decode_kernel<<<B / 16, 256, 0, stream>>>(
        y, hid, P, aW, ab, cW, cb, wih, whh, bih, bhh, fW, fb, out);
}

// Round 2
// 910.113 us; speedup vs baseline: 1.3066x; 1.3066x over previous
//
#include <hip/hip_runtime.h>

#define B 16384
#define ENC_LEN 48
#define ENC_HID 128
#define T_DEC 12

__device__ __forceinline__ float fast_rcp(float x) { return __builtin_amdgcn_rcpf(x); }
__device__ __forceinline__ float fast_exp(float x) { return __expf(x); }
__device__ __forceinline__ float sigmoidf_(float x) { return fast_rcp(1.f + fast_exp(-x)); }
__device__ __forceinline__ float tanhf_(float x) {
    // 1 - 2/(e^{2x}+1); correct saturation for |x| large
    return 1.f - 2.f * fast_rcp(1.f + fast_exp(2.f * x));
}
__device__ __forceinline__ float nan_to_num_(float v) { return (v != v) ? 0.f : v; }

// ---------------- precompute P (unchanged — HBM-bound at ~70 us) ----------------
// P[e*B + b] = float4( enc_row(e,b) . comb_W[i, 0:128] ), i = 0..3
__global__ __launch_bounds__(256) void precompute_P_kernel(
    const float* __restrict__ enc,    // (48, B, 128) f32
    const float* __restrict__ cW,     // (4, 132) f32
    float4* __restrict__ P)
{
    const int l = threadIdx.x & 7;
    const int rowLocal = threadIdx.x >> 3;

    float w[4][4][4];
    #pragma unroll
    for (int i = 0; i < 4; ++i)
        #pragma unroll
        for (int k = 0; k < 4; ++k) {
            float4 t = *(const float4*)(cW + i * 132 + k * 32 + l * 4);
            w[i][k][0] = t.x; w[i][k][1] = t.y; w[i][k][2] = t.z; w[i][k][3] = t.w;
        }

    const int totalRows = ENC_LEN * B;
    const int stride = gridDim.x * 32;
    for (int row = blockIdx.x * 32 + rowLocal; row < totalRows; row += stride) {
        const float* r = enc + (size_t)row * ENC_HID;
        float4 e[4];
        #pragma unroll
        for (int k = 0; k < 4; ++k)
            e[k] = *(const float4*)(r + k * 32 + l * 4);

        float a[4];
        #pragma unroll
        for (int i = 0; i < 4; ++i) {
            float s0 = e[0].x * w[i][0][0] + e[0].y * w[i][0][1] + e[0].z * w[i][0][2] + e[0].w * w[i][0][3];
            float s1 = e[1].x * w[i][1][0] + e[1].y * w[i][1][1] + e[1].z * w[i][1][2] + e[1].w * w[i][1][3];
            float s2 = e[2].x * w[i][2][0] + e[2].y * w[i][2][1] + e[2].z * w[i][2][2] + e[2].w * w[i][2][3];
            float s3 = e[3].x * w[i][3][0] + e[3].y * w[i][3][1] + e[3].z * w[i][3][2] + e[3].w * w[i][3][3];
            a[i] = (s0 + s1) + (s2 + s3);
        }
        #pragma unroll
        for (int m = 1; m < 8; m <<= 1) {
            #pragma unroll
            for (int i = 0; i < 4; ++i)
                a[i] += __shfl_xor(a[i], m, 8);
        }
        if (l == 0) P[row] = make_float4(a[0], a[1], a[2], a[3]);
    }
}

// ---------------- barrier-free decode, spill-free ----------------
// 16 lanes per batch element (4 b per wave, 16 b per 256-thread block).
// Lane q in [0,16) owns attention rows 3q..3q+2 and GRU units {q, q+16}.
// h is exchanged through a tiny per-wave LDS buffer (wave-synchronous: the
// 16-lane group lives inside one wave, so write->read needs no barrier).
// The step is ONE fused c-loop: each float4 of h feeds all 9 dot-product
// accumulators (3 attn rows + 6 GRU gate rows) and then dies -> ~100 live
// VGPRs instead of hf[32]+everything (which spilled at the 64-reg cap and
// generated 1.7 GB of scratch FETCH in round 1).
// __launch_bounds__(256, 2): register cap >=128, no spill; grid still gives
// 4 blocks/CU if the compiler lands <=128 VGPRs.
__global__ __launch_bounds__(256, 2) void decode_kernel(
    const float* __restrict__ y,        // (B,13,4)
    const float* __restrict__ hidden,   // (B,32)
    const float4* __restrict__ P,       // (48,B) f32x4
    const float* __restrict__ aW,       // (48,36)
    const float* __restrict__ ab,       // (48)
    const float* __restrict__ cW,       // (4,132)
    const float* __restrict__ cb,       // (4)
    const float* __restrict__ wih,      // (96,4)
    const float* __restrict__ whh,      // (96,32)
    const float* __restrict__ bih,      // (96)
    const float* __restrict__ bhh,      // (96)
    const float* __restrict__ fW,       // (32)
    const float* __restrict__ fb,       // (1)
    float* __restrict__ out)            // (12,B)
{
    __shared__ __align__(16) float aW_l[48 * 36];    // row e: [0:4]=x-w, [4:36]=h-w
    __shared__ __align__(16) float whh_l[96 * 36];   // row r: [0:32] used, pad 4
    __shared__ __align__(16) float wih_l[96 * 4];
    __shared__ __align__(16) float hbuf[4][144];     // [wave][grp*36 + unit]
    __shared__ float bih_l[96], bhh_l[96], ab_l[48], fW_l[32], cWt_l[16], cb_l[4];

    const int tid = threadIdx.x;

    // ---- one-time weight staging (only sync in the kernel) ----
    for (int i = tid; i < 48 * 36; i += 256) aW_l[i] = aW[i];
    for (int i = tid; i < 96 * 32; i += 256) whh_l[(i >> 5) * 36 + (i & 31)] = whh[i];
    for (int i = tid; i < 96 * 4; i += 256) wih_l[i] = wih[i];
    if (tid < 96) { bih_l[tid] = bih[tid]; bhh_l[tid] = bhh[tid]; }
    if (tid < 48) ab_l[tid] = ab[tid];
    if (tid < 32) fW_l[tid] = fW[tid];
    if (tid < 16) cWt_l[tid] = cW[(tid >> 2) * 132 + 128 + (tid & 3)];
    if (tid < 4)  cb_l[tid] = cb[tid];

    const int lane = tid & 63;
    const int q    = lane & 15;          // role within 16-lane group
    const int w    = tid >> 6;           // wave id within block
    const int grp  = lane >> 4;          // group (batch element) within wave
    const int b    = blockIdx.x * 16 + (tid >> 4);

    // t-invariant P fragments for this lane's 3 attention rows
    const float4 pb0 = P[(size_t)(3 * q + 0) * B + b];
    const float4 pb1 = P[(size_t)(3 * q + 1) * B + b];
    const float4 pb2 = P[(size_t)(3 * q + 2) * B + b];

    // h slice owned by this lane (units q, q+16)
    float h0 = hidden[(size_t)b * 32 + q];
    float h1 = hidden[(size_t)b * 32 + q + 16];

    float xA0 = nan_to_num_(y[(size_t)b * 52 + 0]);
    float xA1 = nan_to_num_(y[(size_t)b * 52 + 1]);
    float xA2 = nan_to_num_(y[(size_t)b * 52 + 2]);
    float xA3 = nan_to_num_(y[(size_t)b * 52 + 3]);

    __syncthreads();

    // t-invariant LDS base pointers
    float* hrow = &hbuf[w][grp * 36];
    const float4* pa0 = (const float4*)(aW_l + (3 * q + 0) * 36 + 4);
    const float4* pa1 = (const float4*)(aW_l + (3 * q + 1) * 36 + 4);
    const float4* pa2 = (const float4*)(aW_l + (3 * q + 2) * 36 + 4);
    const float4* pw0r = (const float4*)(whh_l + (size_t)(q +  0) * 36);
    const float4* pw0z = (const float4*)(whh_l + (size_t)(q + 32) * 36);
    const float4* pw0n = (const float4*)(whh_l + (size_t)(q + 64) * 36);
    const float4* pw1r = (const float4*)(whh_l + (size_t)(q + 16) * 36);
    const float4* pw1z = (const float4*)(whh_l + (size_t)(q + 48) * 36);
    const float4* pw1n = (const float4*)(whh_l + (size_t)(q + 80) * 36);

    const float fb0 = fb[0];

    #pragma unroll 1
    for (int t = 0; t < T_DEC; ++t) {
        // prefetch next y row early (hides HBM/L2 latency under this step)
        float4 yv = make_float4(0.f, 0.f, 0.f, 0.f);
        if (t < T_DEC - 1) yv = *(const float4*)(y + (size_t)b * 52 + (t + 1) * 4);

        // publish h to the wave's group buffer (wave-synchronous, no barrier)
        hrow[q]      = h0;
        hrow[q + 16] = h1;

        // ---- fused c-loop: h float4 -> 9 accumulators, then dies ----
        float s0 = 0.f, s1 = 0.f, s2 = 0.f;
        float gr0 = bhh_l[q],      gz0 = bhh_l[q + 32], gn0 = bhh_l[q + 64];
        float gr1 = bhh_l[q + 16], gz1 = bhh_l[q + 48], gn1 = bhh_l[q + 80];
        #pragma unroll
        for (int c = 0; c < 8; ++c) {
            const float4 hv = *(const float4*)(hrow + 4 * c);
            float4 wv;
            wv = pa0[c];  s0  += wv.x * hv.x + wv.y * hv.y + wv.z * hv.z + wv.w * hv.w;
            wv = pa1[c];  s1  += wv.x * hv.x + wv.y * hv.y + wv.z * hv.z + wv.w * hv.w;
            wv = pa2[c];  s2  += wv.x * hv.x + wv.y * hv.y + wv.z * hv.z + wv.w * hv.w;
            wv = pw0r[c]; gr0 += wv.x * hv.x + wv.y * hv.y + wv.z * hv.z + wv.w * hv.w;
            wv = pw0z[c]; gz0 += wv.x * hv.x + wv.y * hv.y + wv.z * hv.z + wv.w * hv.w;
            wv = pw0n[c]; gn0 += wv.x * hv.x + wv.y * hv.y + wv.z * hv.z + wv.w * hv.w;
            wv = pw1r[c]; gr1 += wv.x * hv.x + wv.y * hv.y + wv.z * hv.z + wv.w * hv.w;
            wv = pw1z[c]; gz1 += wv.x * hv.x + wv.y * hv.y + wv.z * hv.z + wv.w * hv.w;
            wv = pw1n[c]; gn1 += wv.x * hv.x + wv.y * hv.y + wv.z * hv.z + wv.w * hv.w;
        }

        // ---- attention finish: x-part + bias, exp, softmax partials ----
        float4 ax;
        ax = *(const float4*)(aW_l + (3 * q + 0) * 36);
        const float g0 = fast_exp(s0 + ab_l[3 * q + 0]
                                  + ax.x * xA0 + ax.y * xA1 + ax.z * xA2 + ax.w * xA3);
        ax = *(const float4*)(aW_l + (3 * q + 1) * 36);
        const float g1 = fast_exp(s1 + ab_l[3 * q + 1]
                                  + ax.x * xA0 + ax.y * xA1 + ax.z * xA2 + ax.w * xA3);
        ax = *(const float4*)(aW_l + (3 * q + 2) * 36);
        const float g2 = fast_exp(s2 + ab_l[3 * q + 2]
                                  + ax.x * xA0 + ax.y * xA1 + ax.z * xA2 + ax.w * xA3);

        float Sp = g0 + g1 + g2;
        float c0 = g0 * pb0.x + g1 * pb1.x + g2 * pb2.x;
        float c1 = g0 * pb0.y + g1 * pb1.y + g2 * pb2.y;
        float c2 = g0 * pb0.z + g1 * pb1.z + g2 * pb2.z;
        float c3 = g0 * pb0.w + g1 * pb1.w + g2 * pb2.w;

        // butterfly-reduce across the 16-lane group (all lanes get the sums)
        #pragma unroll
        for (int m = 1; m < 16; m <<= 1) {
            Sp += __shfl_xor(Sp, m);
            c0 += __shfl_xor(c0, m);
            c1 += __shfl_xor(c1, m);
            c2 += __shfl_xor(c2, m);
            c3 += __shfl_xor(c3, m);
        }
        const float rs = fast_rcp(Sp);

        const float x20 = c0 * rs + cWt_l[ 0] * xA0 + cWt_l[ 1] * xA1 + cWt_l[ 2] * xA2 + cWt_l[ 3] * xA3 + cb_l[0];
        const float x21 = c1 * rs + cWt_l[ 4] * xA0 + cWt_l[ 5] * xA1 + cWt_l[ 6] * xA2 + cWt_l[ 7] * xA3 + cb_l[1];
        const float x22 = c2 * rs + cWt_l[ 8] * xA0 + cWt_l[ 9] * xA1 + cWt_l[10] * xA2 + cWt_l[11] * xA3 + cb_l[2];
        const float x23 = c3 * rs + cWt_l[12] * xA0 + cWt_l[13] * xA1 + cWt_l[14] * xA2 + cWt_l[15] * xA3 + cb_l[3];

        // ---- GRU finish: input-gate parts + activations ----
        float4 wi;
        wi = *(const float4*)(wih_l + (size_t)(q +  0) * 4);
        const float ir0 = bih_l[q +  0] + wi.x * x20 + wi.y * x21 + wi.z * x22 + wi.w * x23;
        wi = *(const float4*)(wih_l + (size_t)(q + 32) * 4);
        const float iz0 = bih_l[q + 32] + wi.x * x20 + wi.y * x21 + wi.z * x22 + wi.w * x23;
        wi = *(const float4*)(wih_l + (size_t)(q + 64) * 4);
        const float in0 = bih_l[q + 64] + wi.x * x20 + wi.y * x21 + wi.z * x22 + wi.w * x23;
        wi = *(const float4*)(wih_l + (size_t)(q + 16) * 4);
        const float ir1 = bih_l[q + 16] + wi.x * x20 + wi.y * x21 + wi.z * x22 + wi.w * x23;
        wi = *(const float4*)(wih_l + (size_t)(q + 48) * 4);
        const float iz1 = bih_l[q + 48] + wi.x * x20 + wi.y * x21 + wi.z * x22 + wi.w * x23;
        wi = *(const float4*)(wih_l + (size_t)(q + 80) * 4);
        const float in1 = bih_l[q + 80] + wi.x * x20 + wi.y * x21 + wi.z * x22 + wi.w * x23;

        const float r0 = sigmoidf_(ir0 + gr0);
        const float z0 = sigmoidf_(iz0 + gz0);
        const float n0 = tanhf_(in0 + r0 * gn0);
        const float hn0 = (1.f - z0) * n0 + z0 * h0;

        const float r1 = sigmoidf_(ir1 + gr1);
        const float z1 = sigmoidf_(iz1 + gz1);
        const float n1 = tanhf_(in1 + r1 * gn1);
        const float hn1 = (1.f - z1) * n1 + z1 * h1;

        // ---- fc output (butterfly; every lane gets o for the x feedback) ----
        float op = fW_l[q] * hn0 + fW_l[q + 16] * hn1;
        #pragma unroll
        for (int m = 1; m < 16; m <<= 1) op += __shfl_xor(op, m);
        const float o = op + fb0;
        if (q == 0) out[(size_t)t * B + b] = o;

        h0 = hn0; h1 = hn1;
        if (t < T_DEC - 1) { xA0 = yv.y; xA1 = yv.z; xA2 = yv.w; xA3 = o; }
    }
}

extern "C" void kernel_launch(void* const* d_in, const int* in_sizes, int n_in,
                              void* d_out, int out_size, void* d_ws, size_t ws_size,
                              hipStream_t stream)
{
    const float* y   = (const float*)d_in[0];
    const float* enc = (const float*)d_in[1];
    const float* hid = (const float*)d_in[2];
    // d_in[3] = batch_ids (int32, unused by reference)
    const float* aW  = (const float*)d_in[4];
    const float* ab  = (const float*)d_in[5];
    const float* cW  = (const float*)d_in[6];
    const float* cb  = (const float*)d_in[7];
    const float* wih = (const float*)d_in[8];
    const float* whh = (const float*)d_in[9];
    const float* bih = (const float*)d_in[10];
    const float* bhh = (const float*)d_in[11];
    const float* fW  = (const float*)d_in[12];
    const float* fb  = (const float*)d_in[13];
    float* out = (float*)d_out;

    float4* P = (float4*)d_ws;   // 48*B float4 = 12.58 MB (ws proved sufficient)

    precompute_P_kernel<<<4096, 256, 0, stream>>>(enc, cW, P);
    decode_kernel<<<B / 16, 256, 0, stream>>>(
        y, hid, P, aW, ab, cW, cb, wih, whh, bih, bhh, fW, fb, out);
}

// Round 3
// 617.635 us; speedup vs baseline: 1.9253x; 1.4735x over previous
//
#include <hip/hip_runtime.h>

#define B 16384
#define ENC_LEN 48
#define ENC_HID 128
#define T_DEC 12

__device__ __forceinline__ float fast_rcp(float x) { return __builtin_amdgcn_rcpf(x); }
__device__ __forceinline__ float fast_exp(float x) { return __expf(x); }
__device__ __forceinline__ float sigmoidf_(float x) { return fast_rcp(1.f + fast_exp(-x)); }
__device__ __forceinline__ float tanhf_(float x) {
    // 1 - 2/(e^{2x}+1); correct saturation for |x| large
    return 1.f - 2.f * fast_rcp(1.f + fast_exp(2.f * x));
}
__device__ __forceinline__ float nan_to_num_(float v) { return (v != v) ? 0.f : v; }

// ---------------- precompute P (unchanged — HBM-bound at ~70 us) ----------------
// P[e*B + b] = float4( enc_row(e,b) . comb_W[i, 0:128] ), i = 0..3
__global__ __launch_bounds__(256) void precompute_P_kernel(
    const float* __restrict__ enc,    // (48, B, 128) f32
    const float* __restrict__ cW,     // (4, 132) f32
    float4* __restrict__ P)
{
    const int l = threadIdx.x & 7;
    const int rowLocal = threadIdx.x >> 3;

    float w[4][4][4];
    #pragma unroll
    for (int i = 0; i < 4; ++i)
        #pragma unroll
        for (int k = 0; k < 4; ++k) {
            float4 t = *(const float4*)(cW + i * 132 + k * 32 + l * 4);
            w[i][k][0] = t.x; w[i][k][1] = t.y; w[i][k][2] = t.z; w[i][k][3] = t.w;
        }

    const int totalRows = ENC_LEN * B;
    const int stride = gridDim.x * 32;
    for (int row = blockIdx.x * 32 + rowLocal; row < totalRows; row += stride) {
        const float* r = enc + (size_t)row * ENC_HID;
        float4 e[4];
        #pragma unroll
        for (int k = 0; k < 4; ++k)
            e[k] = *(const float4*)(r + k * 32 + l * 4);

        float a[4];
        #pragma unroll
        for (int i = 0; i < 4; ++i) {
            float s0 = e[0].x * w[i][0][0] + e[0].y * w[i][0][1] + e[0].z * w[i][0][2] + e[0].w * w[i][0][3];
            float s1 = e[1].x * w[i][1][0] + e[1].y * w[i][1][1] + e[1].z * w[i][1][2] + e[1].w * w[i][1][3];
            float s2 = e[2].x * w[i][2][0] + e[2].y * w[i][2][1] + e[2].z * w[i][2][2] + e[2].w * w[i][2][3];
            float s3 = e[3].x * w[i][3][0] + e[3].y * w[i][3][1] + e[3].z * w[i][3][2] + e[3].w * w[i][3][3];
            a[i] = (s0 + s1) + (s2 + s3);
        }
        #pragma unroll
        for (int m = 1; m < 8; m <<= 1) {
            #pragma unroll
            for (int i = 0; i < 4; ++i)
                a[i] += __shfl_xor(a[i], m, 8);
        }
        if (l == 0) P[row] = make_float4(a[0], a[1], a[2], a[3]);
    }
}

// ---------------- barrier-free decode, LICM-proofed ----------------
// 16 lanes per batch element. Lane q owns attention rows 3q..3q+2 and GRU
// units {q, q+16}; h is exchanged via a per-wave LDS buffer (wave-synchronous).
// ROUND-2 LESSON: the 72 weight float4s read inside the t-loop have
// loop-invariant LDS addresses -> LICM hoisted all of them into registers
// (288 VGPRs) -> regalloc spilled ~150 to scratch -> 1.1 GB of HBM scratch
// traffic. Fix: route all weight addresses through an opaque
// asm volatile("" : "+v"(qv)) INSIDE the loop so no load can be hoisted;
// weights are re-read from LDS each step (2-way bank aliasing = free).
// Scalars (biases, ab, fW, cWt, cb, fb ~ 50 regs) are deliberately kept in
// registers, preloaded before the loop.
__global__ __launch_bounds__(256, 2) void decode_kernel(
    const float* __restrict__ y,        // (B,13,4)
    const float* __restrict__ hidden,   // (B,32)
    const float4* __restrict__ P,       // (48,B) f32x4
    const float* __restrict__ aW,       // (48,36)
    const float* __restrict__ ab,       // (48)
    const float* __restrict__ cW,       // (4,132)
    const float* __restrict__ cb,       // (4)
    const float* __restrict__ wih,      // (96,4)
    const float* __restrict__ whh,      // (96,32)
    const float* __restrict__ bih,      // (96)
    const float* __restrict__ bhh,      // (96)
    const float* __restrict__ fW,       // (32)
    const float* __restrict__ fb,       // (1)
    float* __restrict__ out)            // (12,B)
{
    __shared__ __align__(16) float aW_l[48 * 36];    // row e: [0:4]=x-w, [4:36]=h-w
    __shared__ __align__(16) float whh_l[96 * 36];   // row r: [0:32] used, pad 4
    __shared__ __align__(16) float wih_l[96 * 4];
    __shared__ __align__(16) float hbuf[4][144];     // [wave][grp*36 + unit]

    const int tid = threadIdx.x;

    // ---- one-time weight staging (only sync in the kernel) ----
    for (int i = tid; i < 48 * 36; i += 256) aW_l[i] = aW[i];
    for (int i = tid; i < 96 * 32; i += 256) whh_l[(i >> 5) * 36 + (i & 31)] = whh[i];
    for (int i = tid; i < 96 * 4; i += 256) wih_l[i] = wih[i];

    const int lane = tid & 63;
    const int q    = lane & 15;          // role within 16-lane group
    const int w    = tid >> 6;           // wave id within block
    const int grp  = lane >> 4;          // group (batch element) within wave
    const int b    = blockIdx.x * 16 + (tid >> 4);

    // t-invariant per-lane data deliberately held in registers
    const float4 pb0 = P[(size_t)(3 * q + 0) * B + b];
    const float4 pb1 = P[(size_t)(3 * q + 1) * B + b];
    const float4 pb2 = P[(size_t)(3 * q + 2) * B + b];

    float h0 = hidden[(size_t)b * 32 + q];
    float h1 = hidden[(size_t)b * 32 + q + 16];

    float xA0 = nan_to_num_(y[(size_t)b * 52 + 0]);
    float xA1 = nan_to_num_(y[(size_t)b * 52 + 1]);
    float xA2 = nan_to_num_(y[(size_t)b * 52 + 2]);
    float xA3 = nan_to_num_(y[(size_t)b * 52 + 3]);

    // scalar weights -> registers (small, one-time global loads, L2-cached)
    const float ab0 = ab[3 * q + 0], ab1 = ab[3 * q + 1], ab2 = ab[3 * q + 2];
    const float bi_r0 = bih[q],      bi_z0 = bih[q + 32], bi_n0 = bih[q + 64];
    const float bi_r1 = bih[q + 16], bi_z1 = bih[q + 48], bi_n1 = bih[q + 80];
    const float bh_r0 = bhh[q],      bh_z0 = bhh[q + 32], bh_n0 = bhh[q + 64];
    const float bh_r1 = bhh[q + 16], bh_z1 = bhh[q + 48], bh_n1 = bhh[q + 80];
    const float fw0 = fW[q], fw1 = fW[q + 16];
    const float fb0 = fb[0];
    float cWt[16], cbv[4];
    #pragma unroll
    for (int i = 0; i < 4; ++i) {
        cbv[i] = cb[i];
        #pragma unroll
        for (int k = 0; k < 4; ++k) cWt[i * 4 + k] = cW[i * 132 + 128 + k];
    }

    __syncthreads();

    float* hrow = &hbuf[w][grp * 36];

    int qv = q;   // opaque role index: re-laundered every iteration

    #pragma unroll 1
    for (int t = 0; t < T_DEC; ++t) {
        // launder qv so every weight address below is NOT loop-invariant
        asm volatile("" : "+v"(qv));

        const float4* pa0  = (const float4*)(aW_l + (3 * qv + 0) * 36 + 4);
        const float4* pa1  = (const float4*)(aW_l + (3 * qv + 1) * 36 + 4);
        const float4* pa2  = (const float4*)(aW_l + (3 * qv + 2) * 36 + 4);
        const float4* pw0r = (const float4*)(whh_l + (size_t)(qv +  0) * 36);
        const float4* pw0z = (const float4*)(whh_l + (size_t)(qv + 32) * 36);
        const float4* pw0n = (const float4*)(whh_l + (size_t)(qv + 64) * 36);
        const float4* pw1r = (const float4*)(whh_l + (size_t)(qv + 16) * 36);
        const float4* pw1z = (const float4*)(whh_l + (size_t)(qv + 48) * 36);
        const float4* pw1n = (const float4*)(whh_l + (size_t)(qv + 80) * 36);

        // prefetch next y row early (hides HBM/L2 latency under this step)
        float4 yv = make_float4(0.f, 0.f, 0.f, 0.f);
        if (t < T_DEC - 1) yv = *(const float4*)(y + (size_t)b * 52 + (t + 1) * 4);

        // publish h to the wave's group buffer (wave-synchronous, no barrier)
        hrow[q]      = h0;
        hrow[q + 16] = h1;

        // ---- fused c-loop: h float4 -> 9 accumulators, then dies ----
        float s0 = 0.f, s1 = 0.f, s2 = 0.f;
        float gr0 = bh_r0, gz0 = bh_z0, gn0 = bh_n0;
        float gr1 = bh_r1, gz1 = bh_z1, gn1 = bh_n1;
        #pragma unroll
        for (int c = 0; c < 8; ++c) {
            const float4 hv = *(const float4*)(hrow + 4 * c);
            float4 wv;
            wv = pa0[c];  s0  += wv.x * hv.x + wv.y * hv.y + wv.z * hv.z + wv.w * hv.w;
            wv = pa1[c];  s1  += wv.x * hv.x + wv.y * hv.y + wv.z * hv.z + wv.w * hv.w;
            wv = pa2[c];  s2  += wv.x * hv.x + wv.y * hv.y + wv.z * hv.z + wv.w * hv.w;
            wv = pw0r[c]; gr0 += wv.x * hv.x + wv.y * hv.y + wv.z * hv.z + wv.w * hv.w;
            wv = pw0z[c]; gz0 += wv.x * hv.x + wv.y * hv.y + wv.z * hv.z + wv.w * hv.w;
            wv = pw0n[c]; gn0 += wv.x * hv.x + wv.y * hv.y + wv.z * hv.z + wv.w * hv.w;
            wv = pw1r[c]; gr1 += wv.x * hv.x + wv.y * hv.y + wv.z * hv.z + wv.w * hv.w;
            wv = pw1z[c]; gz1 += wv.x * hv.x + wv.y * hv.y + wv.z * hv.z + wv.w * hv.w;
            wv = pw1n[c]; gn1 += wv.x * hv.x + wv.y * hv.y + wv.z * hv.z + wv.w * hv.w;
        }

        // ---- attention finish: x-part + bias, exp, softmax partials ----
        float4 ax;
        ax = *(const float4*)(aW_l + (3 * qv + 0) * 36);
        const float g0 = fast_exp(s0 + ab0 + ax.x * xA0 + ax.y * xA1 + ax.z * xA2 + ax.w * xA3);
        ax = *(const float4*)(aW_l + (3 * qv + 1) * 36);
        const float g1 = fast_exp(s1 + ab1 + ax.x * xA0 + ax.y * xA1 + ax.z * xA2 + ax.w * xA3);
        ax = *(const float4*)(aW_l + (3 * qv + 2) * 36);
        const float g2 = fast_exp(s2 + ab2 + ax.x * xA0 + ax.y * xA1 + ax.z * xA2 + ax.w * xA3);

        float Sp = g0 + g1 + g2;
        float c0 = g0 * pb0.x + g1 * pb1.x + g2 * pb2.x;
        float c1 = g0 * pb0.y + g1 * pb1.y + g2 * pb2.y;
        float c2 = g0 * pb0.z + g1 * pb1.z + g2 * pb2.z;
        float c3 = g0 * pb0.w + g1 * pb1.w + g2 * pb2.w;

        // butterfly-reduce across the 16-lane group (all lanes get the sums)
        #pragma unroll
        for (int m = 1; m < 16; m <<= 1) {
            Sp += __shfl_xor(Sp, m);
            c0 += __shfl_xor(c0, m);
            c1 += __shfl_xor(c1, m);
            c2 += __shfl_xor(c2, m);
            c3 += __shfl_xor(c3, m);
        }
        const float rs = fast_rcp(Sp);

        const float x20 = c0 * rs + cWt[ 0] * xA0 + cWt[ 1] * xA1 + cWt[ 2] * xA2 + cWt[ 3] * xA3 + cbv[0];
        const float x21 = c1 * rs + cWt[ 4] * xA0 + cWt[ 5] * xA1 + cWt[ 6] * xA2 + cWt[ 7] * xA3 + cbv[1];
        const float x22 = c2 * rs + cWt[ 8] * xA0 + cWt[ 9] * xA1 + cWt[10] * xA2 + cWt[11] * xA3 + cbv[2];
        const float x23 = c3 * rs + cWt[12] * xA0 + cWt[13] * xA1 + cWt[14] * xA2 + cWt[15] * xA3 + cbv[3];

        // ---- GRU finish: input-gate parts + activations ----
        float4 wi;
        wi = *(const float4*)(wih_l + (size_t)(qv +  0) * 4);
        const float ir0 = bi_r0 + wi.x * x20 + wi.y * x21 + wi.z * x22 + wi.w * x23;
        wi = *(const float4*)(wih_l + (size_t)(qv + 32) * 4);
        const float iz0 = bi_z0 + wi.x * x20 + wi.y * x21 + wi.z * x22 + wi.w * x23;
        wi = *(const float4*)(wih_l + (size_t)(qv + 64) * 4);
        const float in0 = bi_n0 + wi.x * x20 + wi.y * x21 + wi.z * x22 + wi.w * x23;
        wi = *(const float4*)(wih_l + (size_t)(qv + 16) * 4);
        const float ir1 = bi_r1 + wi.x * x20 + wi.y * x21 + wi.z * x22 + wi.w * x23;
        wi = *(const float4*)(wih_l + (size_t)(qv + 48) * 4);
        const float iz1 = bi_z1 + wi.x * x20 + wi.y * x21 + wi.z * x22 + wi.w * x23;
        wi = *(const float4*)(wih_l + (size_t)(qv + 80) * 4);
        const float in1 = bi_n1 + wi.x * x20 + wi.y * x21 + wi.z * x22 + wi.w * x23;

        const float r0 = sigmoidf_(ir0 + gr0);
        const float z0 = sigmoidf_(iz0 + gz0);
        const float n0 = tanhf_(in0 + r0 * gn0);
        const float hn0 = (1.f - z0) * n0 + z0 * h0;

        const float r1 = sigmoidf_(ir1 + gr1);
        const float z1 = sigmoidf_(iz1 + gz1);
        const float n1 = tanhf_(in1 + r1 * gn1);
        const float hn1 = (1.f - z1) * n1 + z1 * h1;

        // ---- fc output (butterfly; every lane gets o for the x feedback) ----
        float op = fw0 * hn0 + fw1 * hn1;
        #pragma unroll
        for (int m = 1; m < 16; m <<= 1) op += __shfl_xor(op, m);
        const float o = op + fb0;
        if (q == 0) out[(size_t)t * B + b] = o;

        h0 = hn0; h1 = hn1;
        if (t < T_DEC - 1) { xA0 = yv.y; xA1 = yv.z; xA2 = yv.w; xA3 = o; }
    }
}

extern "C" void kernel_launch(void* const* d_in, const int* in_sizes, int n_in,
                              void* d_out, int out_size, void* d_ws, size_t ws_size,
                              hipStream_t stream)
{
    const float* y   = (const float*)d_in[0];
    const float* enc = (const float*)d_in[1];
    const float* hid = (const float*)d_in[2];
    // d_in[3] = batch_ids (int32, unused by reference)
    const float* aW  = (const float*)d_in[4];
    const float* ab  = (const float*)d_in[5];
    const float* cW  = (const float*)d_in[6];
    const float* cb  = (const float*)d_in[7];
    const float* wih = (const float*)d_in[8];
    const float* whh = (const float*)d_in[9];
    const float* bih = (const float*)d_in[10];
    const float* bhh = (const float*)d_in[11];
    const float* fW  = (const float*)d_in[12];
    const float* fb  = (const float*)d_in[13];
    float* out = (float*)d_out;

    float4* P = (float4*)d_ws;   // 48*B float4 = 12.58 MB (ws proved sufficient)

    precompute_P_kernel<<<4096, 256, 0, stream>>>(enc, cW, P);
    decode_kernel<<<B / 16, 256, 0, stream>>>(
        y, hid, P, aW, ab, cW, cb, wih, whh, bih, bhh, fW, fb, out);
}